// Round 7
// baseline (81.447 us; speedup 1.0000x reference)
//
#include <hip/hip_runtime.h>

typedef __attribute__((ext_vector_type(4))) float f32x4;
typedef __attribute__((ext_vector_type(8))) short bf16x8;

constexpr int Bsz = 4096, Asz = 32, Isz = 256, Osz = 256;
constexpr int BM = 32, NKT = 8;
constexpr int NBLK = 512;            // 2 blocks/CU resident; each runs 8 tiles

// packed f32x2 -> bf16x2 (RNE); no builtin on gfx950
__device__ inline unsigned cvtpk(float lo, float hi) {
    unsigned r;
    asm("v_cvt_pk_bf16_f32 %0, %1, %2" : "=v"(r) : "v"(lo), "v"(hi));
    return r;
}

// async global->LDS DMA, 16B/lane; dest = wave-uniform base + lane*16 (linear)
__device__ inline void gl_lds16(const void* g, void* l) {
    __builtin_amdgcn_global_load_lds((const __attribute__((address_space(1))) void*)g,
                                     (__attribute__((address_space(3))) void*)l, 16, 0, 0);
}

// ---------------------------------------------------------------------------
// Pre-pack w [A,O,I] f32 -> bf16 fragment-linear: wf[((a*8+kt)*16+nf)*64+lane]
// = the 8 bf16 consumed by lane `lane` of B-fragment (a,kt,nf).
// o = nf*16 + (lane&15), i = kt*32 + (lane>>4)*8 .. +8
// ---------------------------------------------------------------------------
__global__ __launch_bounds__(256) void pack_w(const float* __restrict__ w,
                                              unsigned short* __restrict__ wf) {
    const int gid  = blockIdx.x * 256 + threadIdx.x;
    const int lane = gid & 63, nf = (gid >> 6) & 15, kt = (gid >> 10) & 7, a = gid >> 13;
    const int o  = nf * 16 + (lane & 15);
    const int i0 = kt * 32 + (lane >> 4) * 8;
    const float* s = w + (size_t)(a * Osz + o) * Isz + i0;
    f32x4 lo = *(const f32x4*)s, hi = *(const f32x4*)(s + 4);
    union { bf16x8 v; unsigned u[4]; } r;
    r.u[0] = cvtpk(lo[0], lo[1]); r.u[1] = cvtpk(lo[2], lo[3]);
    r.u[2] = cvtpk(hi[0], hi[1]); r.u[3] = cvtpk(hi[2], hi[3]);
    *(bf16x8*)(wf + (size_t)gid * 8) = r.v;
}

// ---------------------------------------------------------------------------
// Persistent-style GEMM: block p -> xcd k=p&7, slot s=p>>3. 8 tiles/block:
// tile(j2, par) = (a = 4k+j2, brow = 2s+par). A double-buffered in LDS,
// staged ONE TILE AHEAD (DMA has a full tile to land). Raw s_barrier +
// counted vmcnt(32): never drains stores/next-DMAs -> no latency stalls.
// B direct from L2-resident fragment-linear wf.
// ---------------------------------------------------------------------------
__global__ __launch_bounds__(256) void al_gemm(const float* __restrict__ x,
                                               const unsigned short* __restrict__ wf,
                                               const float* __restrict__ bias,
                                               float* __restrict__ out)
{
    __shared__ char sA[2][32768];   // 32 rows x 64 chunks(16B), low-3 chunk-swizzled

    const int p  = blockIdx.x;
    const int k  = p & 7;            // XCD affinity
    const int s  = p >> 3;           // 0..63
    const int a0 = 4 * k;
    const int bE = (2 * s) * BM;     // even-parity batch base
    const int bO = (2 * s + 1) * BM; // odd-parity batch base

    const int t    = threadIdx.x;
    const int wid  = t >> 6;
    const int lane = t & 63;
    const int llo  = lane & 15, lhi = lane >> 4;
    const int nb   = wid * 64;

    // stage one 32x256 f32 tile: wave wid rows wid*8..+7; source chunk-XOR
    // swizzled (linear LDS dest, rule #21)
    auto STAGE = [&](char* buf, int a, int b0) {
#pragma unroll
        for (int jj = 0; jj < 8; ++jj) {
            const int row = wid * 8 + jj;
            const int cq  = (lane & 56) | ((lane & 7) ^ jj);
            const float* src = x + ((size_t)(b0 + row) * Asz + a) * Isz + cq * 4;
            gl_lds16(src, buf + wid * 8192 + jj * 1024);
        }
    };

    // compute-side LDS addr: row=m*16+llo, phys chunk = kt*8 + ((2*lhi)^(llo&7))
    const int abase = llo * 1024 + (((2 * lhi) ^ (llo & 7)) << 4);

    auto TILE = [&](const char* buf, int a, int b0) {
        const unsigned short* bp = wf + (size_t)a * (Osz * Isz) + wid * 2048 + lane * 8;
        f32x4 acc[2][4];
#pragma unroll
        for (int n = 0; n < 4; ++n) {
            const float bv = bias[a * Osz + nb + n * 16 + llo];
#pragma unroll
            for (int m = 0; m < 2; ++m) acc[m][n] = (f32x4)(bv);
        }
#pragma unroll
        for (int kt = 0; kt < NKT; ++kt) {
            bf16x8 bF[4];
#pragma unroll
            for (int n = 0; n < 4; ++n)
                bF[n] = *(const bf16x8*)(bp + (size_t)kt * 8192 + n * 512);
            bf16x8 aF[2];
#pragma unroll
            for (int m = 0; m < 2; ++m) {
                const int ad = m * 16384 + abase + kt * 128;
                f32x4 lo = *(const f32x4*)&buf[ad];
                f32x4 hi = *(const f32x4*)&buf[ad ^ 16];
                union { bf16x8 v; unsigned u[4]; } r;
                r.u[0] = cvtpk(lo[0], lo[1]); r.u[1] = cvtpk(lo[2], lo[3]);
                r.u[2] = cvtpk(hi[0], hi[1]); r.u[3] = cvtpk(hi[2], hi[3]);
                aF[m] = r.v;
            }
#pragma unroll
            for (int m = 0; m < 2; ++m)
#pragma unroll
                for (int n = 0; n < 4; ++n)
                    acc[m][n] = __builtin_amdgcn_mfma_f32_16x16x32_bf16(aF[m], bF[n], acc[m][n], 0, 0, 0);
        }
        // D[row = m*16 + lhi*4 + r][col = nb + n*16 + llo]
#pragma unroll
        for (int n = 0; n < 4; ++n) {
            const int col = nb + n * 16 + llo;
#pragma unroll
            for (int m = 0; m < 2; ++m) {
                const int row = b0 + m * 16 + lhi * 4;
                float* op = out + ((size_t)row * Asz + a) * Osz + col;
#pragma unroll
                for (int r = 0; r < 4; ++r)
                    op[(size_t)r * Asz * Osz] = acc[m][n][r];
            }
        }
    };

    // ---- prologue: fill both buffers ----
    STAGE(sA[0], a0, bE);
    STAGE(sA[1], a0, bO);
    asm volatile("s_waitcnt vmcnt(8)" ::: "memory");   // buf0's 8 DMAs done (own)
    __builtin_amdgcn_sched_barrier(0);
    __builtin_amdgcn_s_barrier();                      // all waves: buf0 ready

#pragma unroll
    for (int j2 = 0; j2 < 4; ++j2) {
        // ---- even tile (buf0) ----
        TILE(sA[0], a0 + j2, bE);
        // outstanding: [stores prev-odd (done)] [DMA buf1 (8)] [stores even (32)]
        asm volatile("s_waitcnt vmcnt(32)" ::: "memory");  // -> buf1 DMAs done
        __builtin_amdgcn_sched_barrier(0);
        __builtin_amdgcn_s_barrier();                      // everyone done with buf0
        if (j2 < 3) STAGE(sA[0], a0 + j2 + 1, bE);         // refill buf0, 1 tile ahead

        // ---- odd tile (buf1) ----
        TILE(sA[1], a0 + j2, bO);
        // outstanding: [stores even (old)] [DMA buf0 (8)] [stores odd (32)]
        asm volatile("s_waitcnt vmcnt(32)" ::: "memory");  // -> buf0 DMAs done
        __builtin_amdgcn_sched_barrier(0);
        __builtin_amdgcn_s_barrier();                      // everyone done with buf1
        if (j2 < 3) STAGE(sA[1], a0 + j2 + 1, bO);         // refill buf1
    }
}

extern "C" void kernel_launch(void* const* d_in, const int* in_sizes, int n_in,
                              void* d_out, int out_size, void* d_ws, size_t ws_size,
                              hipStream_t stream) {
    const float* x    = (const float*)d_in[0];
    const float* w    = (const float*)d_in[1];
    const float* bias = (const float*)d_in[2];
    float* out        = (float*)d_out;
    unsigned short* wf = (unsigned short*)d_ws;   // 4 MB

    pack_w<<<dim3(Asz * NKT * 16 * 64 / 256), dim3(256), 0, stream>>>(w, wf);
    al_gemm<<<dim3(NBLK), dim3(256), 0, stream>>>(x, wf, bias, out);
}